// Round 5
// baseline (67.467 us; speedup 1.0000x reference)
//
#include <hip/hip_runtime.h>

#define N_SLOTS 65536
#define DIM 128
#define B_SZ 4096
#define K_TOP 8
#define UPDATE_RATE 0.1f
#define MOMENTUM 0.9f
#define GATE_THRESH 0.01f

typedef float f32x4 __attribute__((ext_vector_type(4)));

// ---------------------------------------------------------------------------
// Keys pass: outk = mk + MOMENTUM * km. Exactly 3 chip-wide streams.
// Counts scatter-add fused into the first 128 blocks; the kernel-end barrier
// orders it before the scatter kernel reads counts.
// 4096 blocks x 256 threads, 2 f32x4 per thread, lane-contiguous.
// ---------------------------------------------------------------------------
__global__ void __launch_bounds__(256) mw_keys_kernel(
        const f32x4* __restrict__ mk,
        const f32x4* __restrict__ km,
        f32x4* __restrict__ outk,
        const float* __restrict__ gate,
        const int* __restrict__ top_idx,
        float* __restrict__ counts) {
    int bid = blockIdx.x;
    int gtid = bid * 256 + threadIdx.x;

    // fused counts scatter (first 128 blocks only)
    if (gtid < B_SZ * K_TOP) {
        int a = gtid >> 3;
        float g = gate[a];
        float w = (g > GATE_THRESH) ? g * UPDATE_RATE : 0.0f;
        if (w != 0.0f) {
            atomicAdd(&counts[top_idx[gtid]], w);
        }
    }

    int base = bid * 512 + threadIdx.x;
    f32x4 a0 = mk[base];
    f32x4 a1 = mk[base + 256];
    f32x4 b0 = km[base];
    f32x4 b1 = km[base + 256];
    outk[base]       = a0 + MOMENTUM * b0;
    outk[base + 256] = a1 + MOMENTUM * b1;
}

// ---------------------------------------------------------------------------
// Values pass: outv = mv + MOMENTUM * vm. Exactly 3 chip-wide streams.
// ---------------------------------------------------------------------------
__global__ void __launch_bounds__(256) mw_values_kernel(
        const f32x4* __restrict__ mv,
        const f32x4* __restrict__ vm,
        f32x4* __restrict__ outv) {
    int base = blockIdx.x * 512 + threadIdx.x;
    f32x4 a0 = mv[base];
    f32x4 a1 = mv[base + 256];
    f32x4 b0 = vm[base];
    f32x4 b1 = vm[base + 256];
    outv[base]       = a0 + MOMENTUM * b0;
    outv[base + 256] = a1 + MOMENTUM * b1;
}

// ---------------------------------------------------------------------------
// Scatter normalized updates. One block per write `a`: lanes 0..127 own the
// key row, 128..255 the value row; k-loop inside so q/v load once per block.
// ---------------------------------------------------------------------------
__global__ void __launch_bounds__(256) mw_scatter_kernel(
        const float* __restrict__ q,
        const float* __restrict__ v,
        const float* __restrict__ gate,
        const int* __restrict__ top_idx,
        const float* __restrict__ counts,
        float* __restrict__ outk,
        float* __restrict__ outv) {
    int a = blockIdx.x;                   // 0 .. B-1
    float g = gate[a];
    float w = (g > GATE_THRESH) ? g * UPDATE_RATE : 0.0f;
    if (w == 0.0f) return;                // block-uniform exit
    int t = threadIdx.x;
    int d = t & (DIM - 1);
    bool is_key = (t < DIM);
    float x = is_key ? q[a * DIM + d] : v[a * DIM + d];
    float* base = is_key ? outk : outv;
    float wm = (1.0f - MOMENTUM) * w;
#pragma unroll
    for (int k = 0; k < K_TOP; ++k) {
        int s = top_idx[a * K_TOP + k];
        float cnt = counts[s];
        float denom = (cnt > 0.0f) ? cnt : 1.0f;
        float c = wm / denom;
        atomicAdd(&base[s * DIM + d], c * x);
    }
}

extern "C" void kernel_launch(void* const* d_in, const int* in_sizes, int n_in,
                              void* d_out, int out_size, void* d_ws, size_t ws_size,
                              hipStream_t stream) {
    const float* memory_keys    = (const float*)d_in[0];
    const float* memory_values  = (const float*)d_in[1];
    const float* write_query    = (const float*)d_in[2];
    const float* write_value    = (const float*)d_in[3];
    const float* gate_weights   = (const float*)d_in[4];
    const int*   top_indices    = (const int*)d_in[5];
    const float* key_momentum   = (const float*)d_in[6];
    const float* value_momentum = (const float*)d_in[7];

    float* out  = (float*)d_out;
    float* outk = out;
    float* outv = out + (size_t)N_SLOTS * DIM;

    float* counts = (float*)d_ws;         // 65536 floats = 256 KB

    // 0) zero the counts accumulator (deterministic per call)
    hipMemsetAsync(counts, 0, N_SLOTS * sizeof(float), stream);

    // 1) keys half (3 streams) + fused counts
    {
        int grid = N_SLOTS * DIM / 4 / 512;    // 4096 blocks
        mw_keys_kernel<<<grid, 256, 0, stream>>>(
            (const f32x4*)memory_keys, (const f32x4*)key_momentum,
            (f32x4*)outk, gate_weights, top_indices, counts);
    }

    // 2) values half (3 streams)
    {
        int grid = N_SLOTS * DIM / 4 / 512;    // 4096 blocks
        mw_values_kernel<<<grid, 256, 0, stream>>>(
            (const f32x4*)memory_values, (const f32x4*)value_momentum,
            (f32x4*)outv);
    }

    // 3) scatter normalized updates into the output
    {
        mw_scatter_kernel<<<B_SZ, 256, 0, stream>>>(
            write_query, write_value, gate_weights, top_indices, counts,
            outk, outv);
    }
}